// Round 3
// baseline (78.158 us; speedup 1.0000x reference)
//
#include <hip/hip_runtime.h>
#include <math.h>

#define DT 0.005f
#define NBLOCKS 1024
#define NTHREADS 256

typedef float fvec4 __attribute__((ext_vector_type(4)));
typedef int   ivec4 __attribute__((ext_vector_type(4)));

__device__ __forceinline__ fvec4 ntload4f(const float* p) {
    return __builtin_nontemporal_load(reinterpret_cast<const fvec4*>(p));
}
__device__ __forceinline__ ivec4 ntload4i(const int* p) {
    return __builtin_nontemporal_load(reinterpret_cast<const ivec4*>(p));
}
__device__ __forceinline__ float ntloadf(const float* p) {
    return __builtin_nontemporal_load(p);
}

__global__ __launch_bounds__(NTHREADS) void pos_loss_partial(
    const float* __restrict__ quat,     // B*4
    const float* __restrict__ tpos,     // B*3
    const float* __restrict__ bias,     // B*3
    const float* __restrict__ batchX,   // B*S*F
    const float* __restrict__ pos_all,  // N*3
    const float* __restrict__ vel_all,  // N*3
    const float* __restrict__ grav,     // 3
    const int*   __restrict__ indices,  // B
    const int*   __restrict__ seq_len_p,// 1
    int B, int SF,
    float* __restrict__ partials)       // NBLOCKS
{
    const int S = *seq_len_p;
    const int F = SF / S;
    const int last_off = (S - 1) * F;
    const float gx = grav[0], gy = grav[1], gz = grav[2];
    const float half_dt2 = 0.5f * DT * DT;

    float hsum = 0.f;
    const int nv = B >> 2;  // number of 4-element chunks
    const int stride = gridDim.x * blockDim.x;

    for (int c = blockIdx.x * blockDim.x + threadIdx.x; c < nv; c += stride) {
        const size_t i0 = (size_t)c << 2;

        // ---- streaming loads, all vectorized + nontemporal ----
        ivec4 iv = ntload4i(indices + i0);

        fvec4 qa[4];
        qa[0] = ntload4f(quat + i0 * 4 + 0);
        qa[1] = ntload4f(quat + i0 * 4 + 4);
        qa[2] = ntload4f(quat + i0 * 4 + 8);
        qa[3] = ntload4f(quat + i0 * 4 + 12);

        float tpf[12], bpf[12];
        {
            fvec4 t0 = ntload4f(tpos + i0 * 3 + 0);
            fvec4 t1 = ntload4f(tpos + i0 * 3 + 4);
            fvec4 t2 = ntload4f(tpos + i0 * 3 + 8);
            *reinterpret_cast<fvec4*>(&tpf[0]) = t0;
            *reinterpret_cast<fvec4*>(&tpf[4]) = t1;
            *reinterpret_cast<fvec4*>(&tpf[8]) = t2;
            fvec4 b0 = ntload4f(bias + i0 * 3 + 0);
            fvec4 b1 = ntload4f(bias + i0 * 3 + 4);
            fvec4 b2 = ntload4f(bias + i0 * 3 + 8);
            *reinterpret_cast<fvec4*>(&bpf[0]) = b0;
            *reinterpret_cast<fvec4*>(&bpf[4]) = b1;
            *reinterpret_cast<fvec4*>(&bpf[8]) = b2;
        }

        // batchX last-sample accel (strided 12B reads, nontemporal)
        float axr[4], ayr[4], azr[4];
        #pragma unroll
        for (int e = 0; e < 4; ++e) {
            const float* xb = batchX + (i0 + e) * SF + last_off;
            axr[e] = ntloadf(xb + 0);
            ayr[e] = ntloadf(xb + 1);
            azr[e] = ntloadf(xb + 2);
        }

        // ---- 8 independent gathers, issued back-to-back ----
        int idxs[4] = {iv.x, iv.y, iv.z, iv.w};
        float p0a[4][3], v0a[4][3];
        #pragma unroll
        for (int e = 0; e < 4; ++e) {
            int ix = idxs[e] - (S - 1);
            if (ix < 0) ix = 0;
            const float* pp = pos_all + (size_t)ix * 3;
            p0a[e][0] = pp[0]; p0a[e][1] = pp[1]; p0a[e][2] = pp[2];
            const float* vp = vel_all + (size_t)ix * 3;
            v0a[e][0] = vp[0]; v0a[e][1] = vp[1]; v0a[e][2] = vp[2];
        }

        // ---- compute ----
        #pragma unroll
        for (int e = 0; e < 4; ++e) {
            float qx = qa[e].x, qy = qa[e].y, qz = qa[e].z, qw = qa[e].w;
            float ax = axr[e] - bpf[3 * e + 0];
            float ay = ayr[e] - bpf[3 * e + 1];
            float az = azr[e] - bpf[3 * e + 2];

            // t = q * (0, a)
            float t0 = -(qy * ax + qz * ay + qw * az);
            float t1 =   qx * ax + qz * az - qw * ay;
            float t2 =   qx * ay - qy * az + qw * ax;
            float t3 =   qx * az + qy * ay - qz * ax;
            // (t * q_conj) vector part
            float rx = -t0 * qy + t1 * qx - t2 * qw + t3 * qz;
            float ry = -t0 * qz + t1 * qw + t2 * qx - t3 * qy;
            float rz = -t0 * qw - t1 * qz + t2 * qy + t3 * qx;

            float px = p0a[e][0] + v0a[e][0] * DT + half_dt2 * gx + half_dt2 * rx;
            float py = p0a[e][1] + v0a[e][1] * DT + half_dt2 * gy + half_dt2 * ry;
            float pz = p0a[e][2] + v0a[e][2] * DT + half_dt2 * gz + half_dt2 * rz;

            float dx = px - tpf[3 * e + 0];
            float dy = py - tpf[3 * e + 1];
            float dz = pz - tpf[3 * e + 2];

            float adx = fabsf(dx), ady = fabsf(dy), adz = fabsf(dz);
            hsum += (adx < 1.f) ? 0.5f * dx * dx : adx - 0.5f;
            hsum += (ady < 1.f) ? 0.5f * dy * dy : ady - 0.5f;
            hsum += (adz < 1.f) ? 0.5f * dz * dz : adz - 0.5f;
        }
    }

    // scalar tail for B % 4 (empty when B is a multiple of 4)
    for (int i = (nv << 2) + blockIdx.x * blockDim.x + threadIdx.x; i < B;
         i += stride) {
        float qx = quat[(size_t)i * 4 + 0], qy = quat[(size_t)i * 4 + 1];
        float qz = quat[(size_t)i * 4 + 2], qw = quat[(size_t)i * 4 + 3];
        float bx = bias[(size_t)i * 3 + 0], by = bias[(size_t)i * 3 + 1],
              bz = bias[(size_t)i * 3 + 2];
        const float* xb = batchX + (size_t)i * SF + last_off;
        float ax = xb[0] - bx, ay = xb[1] - by, az = xb[2] - bz;
        int ix = indices[i] - (S - 1);
        if (ix < 0) ix = 0;
        const float* pp = pos_all + (size_t)ix * 3;
        const float* vp = vel_all + (size_t)ix * 3;

        float t0 = -(qy * ax + qz * ay + qw * az);
        float t1 =   qx * ax + qz * az - qw * ay;
        float t2 =   qx * ay - qy * az + qw * ax;
        float t3 =   qx * az + qy * ay - qz * ax;
        float rx = -t0 * qy + t1 * qx - t2 * qw + t3 * qz;
        float ry = -t0 * qz + t1 * qw + t2 * qx - t3 * qy;
        float rz = -t0 * qw - t1 * qz + t2 * qy + t3 * qx;

        float px = pp[0] + vp[0] * DT + half_dt2 * gx + half_dt2 * rx;
        float py = pp[1] + vp[1] * DT + half_dt2 * gy + half_dt2 * ry;
        float pz = pp[2] + vp[2] * DT + half_dt2 * gz + half_dt2 * rz;

        float dx = px - tpos[(size_t)i * 3 + 0];
        float dy = py - tpos[(size_t)i * 3 + 1];
        float dz = pz - tpos[(size_t)i * 3 + 2];

        float adx = fabsf(dx), ady = fabsf(dy), adz = fabsf(dz);
        hsum += (adx < 1.f) ? 0.5f * dx * dx : adx - 0.5f;
        hsum += (ady < 1.f) ? 0.5f * dy * dy : ady - 0.5f;
        hsum += (adz < 1.f) ? 0.5f * dz * dz : adz - 0.5f;
    }

    // wave-64 reduce
    for (int off = 32; off > 0; off >>= 1)
        hsum += __shfl_down(hsum, off);

    __shared__ float wsum[NTHREADS / 64];
    int lane = threadIdx.x & 63;
    int wid  = threadIdx.x >> 6;
    if (lane == 0) wsum[wid] = hsum;
    __syncthreads();

    if (threadIdx.x == 0) {
        float s = 0.f;
        for (int w = 0; w < NTHREADS / 64; ++w) s += wsum[w];
        partials[blockIdx.x] = s;
    }
}

__global__ __launch_bounds__(NTHREADS) void pos_loss_finish(
    const float* __restrict__ partials, int nb, float inv_cnt,
    float* __restrict__ out)
{
    float s = 0.f;
    for (int i = threadIdx.x; i < nb; i += NTHREADS) s += partials[i];

    for (int off = 32; off > 0; off >>= 1)
        s += __shfl_down(s, off);

    __shared__ float wsum[NTHREADS / 64];
    int lane = threadIdx.x & 63;
    int wid  = threadIdx.x >> 6;
    if (lane == 0) wsum[wid] = s;
    __syncthreads();

    if (threadIdx.x == 0) {
        float tot = 0.f;
        for (int w = 0; w < NTHREADS / 64; ++w) tot += wsum[w];
        out[0] = tot * inv_cnt;
    }
}

extern "C" void kernel_launch(void* const* d_in, const int* in_sizes, int n_in,
                              void* d_out, int out_size, void* d_ws, size_t ws_size,
                              hipStream_t stream) {
    const float* quat    = (const float*)d_in[0];
    const float* tpos    = (const float*)d_in[1];
    const float* bias    = (const float*)d_in[2];
    const float* batchX  = (const float*)d_in[3];
    const float* pos_all = (const float*)d_in[4];
    const float* vel_all = (const float*)d_in[5];
    const float* grav    = (const float*)d_in[6];
    const int*   indices = (const int*)d_in[7];
    const int*   seqlen  = (const int*)d_in[8];

    const int B  = in_sizes[0] / 4;
    const int SF = in_sizes[3] / B;

    float* partials = (float*)d_ws;
    float inv_cnt = (float)(1.0 / (3.0 * (double)B));

    pos_loss_partial<<<NBLOCKS, NTHREADS, 0, stream>>>(
        quat, tpos, bias, batchX, pos_all, vel_all, grav, indices, seqlen,
        B, SF, partials);

    pos_loss_finish<<<1, NTHREADS, 0, stream>>>(
        partials, NBLOCKS, inv_cnt, (float*)d_out);
}